// Round 9
// baseline (502.369 us; speedup 1.0000x reference)
//
#include <hip/hip_runtime.h>

#define N_NODES 203
#define NPC 29            // nodes per client = K of the matmul
#define ODIM 256
#define ROWLEN (2048 * ODIM)    // 524288
#define NSPLIT 4
#define NCHUNK 51               // ceil(203/4)

typedef float v4f __attribute__((ext_vector_type(4)));

// Kernel A: dinv[r] = 1/sqrt(1 + sum_j adj[r][j]); one wave per row.
__global__ __launch_bounds__(64) void dinv_kernel(
    const float* __restrict__ adj, float* __restrict__ dinv) {
    const int r = blockIdx.x;
    const int lane = threadIdx.x;
    float s = (lane == 0) ? 1.0f : 0.0f;   // self-loop +1
    for (int j = lane; j < N_NODES; j += 64) s += adj[r * N_NODES + j];
#pragma unroll
    for (int off = 32; off; off >>= 1) s += __shfl_down(s, off);
    if (lane == 0) dinv[r] = 1.0f / sqrtf(s);
}

// Kernel B: col[i*NPC+k] = dinv[i] * (adj[i][j] + (i==j)) * dinv[j], j=id*NPC+k
__global__ __launch_bounds__(256) void col_kernel(
    const float* __restrict__ adj, const float* __restrict__ dinv,
    const int* __restrict__ idp, float* __restrict__ col) {
    const int idx = blockIdx.x * 256 + threadIdx.x;
    if (idx >= N_NODES * NPC) return;
    const int i = idx / NPC;
    const int k = idx - i * NPC;
    const int j = (*idp) * NPC + k;
    float a = adj[i * N_NODES + j] + (i == j ? 1.0f : 0.0f);
    col[idx] = dinv[i] * a * dinv[j];
}

// Kernel C: out[b][n][d] = sum_k col[n][k] * X[k][b*ODIM+d]
// col reads are wave-uniform -> scalar s_load path. X in registers
// (float4/thread, 16B/lane coalesced loads+stores). Plain stores —
// NT stores raced with the harness's cached poison fills on graph replay (R7).
__global__ __launch_bounds__(256) void gcn_mm_kernel(
    const float* __restrict__ X, const float* __restrict__ col,
    float* __restrict__ out) {
    const int n0 = blockIdx.y * NCHUNK;
    const int n1 = (n0 + NCHUNK < N_NODES) ? (n0 + NCHUNK) : N_NODES;

    const int j0 = (blockIdx.x * 256 + threadIdx.x) * 4;
    v4f x[NPC];
#pragma unroll
    for (int k = 0; k < NPC; ++k)
        x[k] = *(const v4f*)(X + (size_t)k * ROWLEN + j0);

    const int b = j0 >> 8;          // j0 / ODIM
    const int d = j0 & (ODIM - 1);
    float* obase = out + (size_t)b * (N_NODES * ODIM) + d;

#pragma unroll 2
    for (int n = n0; n < n1; ++n) {
        // wave-uniform loads -> scalar pipe (s_load_dwordx8 clusters)
        float c[NPC];
        const float* cn = col + n * NPC;
#pragma unroll
        for (int k = 0; k < NPC; ++k) c[k] = cn[k];

        v4f acc = {0.f, 0.f, 0.f, 0.f};
#pragma unroll
        for (int k = 0; k < NPC; ++k) {
            acc.x = fmaf(c[k], x[k].x, acc.x);
            acc.y = fmaf(c[k], x[k].y, acc.y);
            acc.z = fmaf(c[k], x[k].z, acc.z);
            acc.w = fmaf(c[k], x[k].w, acc.w);
        }
        *(v4f*)(obase + (size_t)n * ODIM) = acc;
    }
}

extern "C" void kernel_launch(void* const* d_in, const int* in_sizes, int n_in,
                              void* d_out, int out_size, void* d_ws, size_t ws_size,
                              hipStream_t stream) {
    const float* adj = (const float*)d_in[0];   // (203, 203)
    const float* X   = (const float*)d_in[1];   // (29, 524288)
    const int*   idp = (const int*)d_in[4];     // scalar id
    float* out  = (float*)d_out;                // (2048, 203, 256)
    float* dinv = (float*)d_ws;                 // 203 floats
    float* col  = (float*)d_ws + 256;           // 203*29 floats

    dinv_kernel<<<N_NODES, 64, 0, stream>>>(adj, dinv);
    col_kernel<<<(N_NODES * NPC + 255) / 256, 256, 0, stream>>>(adj, dinv, idp, col);

    dim3 grid(ROWLEN / (256 * 4), NSPLIT);      // (512, 4) = 2048 blocks
    gcn_mm_kernel<<<grid, 256, 0, stream>>>(X, col, out);
}